// Round 4
// baseline (717.852 us; speedup 1.0000x reference)
//
#include <hip/hip_runtime.h>

// Scatter-mean voxel pooling via counting sort — no global fp atomics.
// N=1e6 points, C=64 channels, K=64 grid (262144 cells).
//
// Round-4 change: reduce_cells restructured around the fact that consecutive
// cells own CONTIGUOUS order-spans. One block = 64 consecutive cells:
// coalesced metadata load, coalesced LDS staging of the order span
// (order[] + ordcell[]), then 16 lane-groups process slots round-robin
// (independent iterations -> gather latency hidden), accumulating into an
// LDS acc[64][64] via ds_add_f32. Coalesced epilogue store. This removes the
// per-cell serial pointer chain that limited rounds 2-3 to ~162 us.

#define KGRID  64
#define NCH    64
#define NCELLS (KGRID * KGRID * KGRID)    // 262144
#define SCAN_CHUNK  1024
#define SCAN_BLOCKS (NCELLS / SCAN_CHUNK) // 256
#define CELLS_PER_BLOCK 64
#define MAXSPAN 768   // LDS staging capacity; avg span=243, 25 sigma margin

__device__ __forceinline__ int cell_of(float px, float py, float pz) {
    int ix = min(max((int)floorf((px + 1.0f) * 32.0f), 0), KGRID - 1);
    int iy = min(max((int)floorf((py + 1.0f) * 32.0f), 0), KGRID - 1);
    int iz = min(max((int)floorf((pz + 1.0f) * 32.0f), 0), KGRID - 1);
    return (ix << 12) | (iy << 6) | iz;
}

// 4 points per thread: 3 float4 loads = 12 floats = 4 points.
__global__ __launch_bounds__(256) void compute_cells(
    const float* __restrict__ pts,
    int* __restrict__ cellid,
    int* __restrict__ counts,
    int n)
{
    int t = blockIdx.x * blockDim.x + threadIdx.x;
    int p0 = t * 4;
    if (p0 >= n) return;
    if (p0 + 4 <= n) {
        const float4* p4 = (const float4*)(pts + (size_t)p0 * 3);
        float4 a = p4[0], b = p4[1], c = p4[2];
        int4 cid;
        cid.x = cell_of(a.x, a.y, a.z);
        cid.y = cell_of(a.w, b.x, b.y);
        cid.z = cell_of(b.z, b.w, c.x);
        cid.w = cell_of(c.y, c.z, c.w);
        *(int4*)(cellid + p0) = cid;
        atomicAdd(&counts[cid.x], 1);
        atomicAdd(&counts[cid.y], 1);
        atomicAdd(&counts[cid.z], 1);
        atomicAdd(&counts[cid.w], 1);
    } else {
        for (int p = p0; p < n; ++p) {
            int c = cell_of(pts[3*p], pts[3*p+1], pts[3*p+2]);
            cellid[p] = c;
            atomicAdd(&counts[c], 1);
        }
    }
}

// Per-chunk sums (1024 ints per block).
__global__ __launch_bounds__(256) void scan_reduce(
    const int* __restrict__ counts, int* __restrict__ blocksums)
{
    __shared__ int s[256];
    int b = blockIdx.x, t = threadIdx.x;
    const int4* c4 = (const int4*)(counts + b * SCAN_CHUNK);
    int4 v = c4[t];
    s[t] = v.x + v.y + v.z + v.w;
    __syncthreads();
    for (int off = 128; off > 0; off >>= 1) {
        if (t < off) s[t] += s[t + off];
        __syncthreads();
    }
    if (t == 0) blocksums[b] = s[0];
}

// Exclusive scan of the 256 block sums (single block).
__global__ __launch_bounds__(256) void scan_blocksums(
    const int* __restrict__ blocksums, int* __restrict__ blockbase)
{
    __shared__ int s[256];
    int t = threadIdx.x;
    int v = blocksums[t];
    s[t] = v;
    __syncthreads();
    for (int off = 1; off < 256; off <<= 1) {
        int x = (t >= off) ? s[t - off] : 0;
        __syncthreads();
        s[t] += x;
        __syncthreads();
    }
    blockbase[t] = s[t] - v;   // exclusive
}

// Chunk-local exclusive scan + block base -> final offsets.
__global__ __launch_bounds__(256) void scan_write(
    const int* __restrict__ counts,
    const int* __restrict__ blockbase,
    int* __restrict__ offsets)
{
    __shared__ int s[256];
    int b = blockIdx.x, t = threadIdx.x;
    const int4* c4 = (const int4*)(counts + b * SCAN_CHUNK);
    int4 v = c4[t];
    int tsum = v.x + v.y + v.z + v.w;
    s[t] = tsum;
    __syncthreads();
    for (int off = 1; off < 256; off <<= 1) {
        int x = (t >= off) ? s[t - off] : 0;
        __syncthreads();
        s[t] += x;
        __syncthreads();
    }
    int base = blockbase[b] + (s[t] - tsum);  // exclusive across chunk
    int4 o;
    o.x = base;
    o.y = base + v.x;
    o.z = base + v.x + v.y;
    o.w = base + v.x + v.y + v.z;
    ((int4*)(offsets + b * SCAN_CHUNK))[t] = o;
}

// 4 points per thread; also emits ordcell (cell id per sorted slot).
__global__ __launch_bounds__(256) void build_order(
    const int* __restrict__ cellid,
    int* __restrict__ offsets,
    int* __restrict__ order,
    int* __restrict__ ordcell,
    int n)
{
    int t = blockIdx.x * blockDim.x + threadIdx.x;
    int p0 = t * 4;
    if (p0 >= n) return;
    if (p0 + 4 <= n) {
        int4 cid = *(const int4*)(cellid + p0);
        int s0 = atomicAdd(&offsets[cid.x], 1);
        int s1 = atomicAdd(&offsets[cid.y], 1);
        int s2 = atomicAdd(&offsets[cid.z], 1);
        int s3 = atomicAdd(&offsets[cid.w], 1);
        order[s0] = p0 + 0;  ordcell[s0] = cid.x;
        order[s1] = p0 + 1;  ordcell[s1] = cid.y;
        order[s2] = p0 + 2;  ordcell[s2] = cid.z;
        order[s3] = p0 + 3;  ordcell[s3] = cid.w;
    } else {
        for (int p = p0; p < n; ++p) {
            int c = cellid[p];
            int slot = atomicAdd(&offsets[c], 1);
            order[slot] = p;  ordcell[slot] = c;
        }
    }
}

// One block = 64 consecutive cells. Slot-parallel gather into LDS accumulators.
__global__ __launch_bounds__(256) void reduce_cells(
    const float4* __restrict__ feat4,
    const int* __restrict__ order,
    const int* __restrict__ ordcell,
    const int* __restrict__ offsets,   // == end of each cell's range
    const int* __restrict__ counts,    // == length
    float4* __restrict__ out4)
{
    __shared__ float acc[CELLS_PER_BLOCK * NCH];   // 16 KB
    __shared__ int s_cnt[CELLS_PER_BLOCK];
    __shared__ int s_order[MAXSPAN];
    __shared__ int s_ocell[MAXSPAN];
    __shared__ int s_meta[2];                      // {block_start, span}

    const int tid = threadIdx.x;
    const int c0  = blockIdx.x * CELLS_PER_BLOCK;

    // Zero accumulators (16 KB).
    float4* acc4 = (float4*)acc;
    #pragma unroll
    for (int i = 0; i < 4; ++i)
        acc4[tid + 256 * i] = make_float4(0.f, 0.f, 0.f, 0.f);

    if (tid < CELLS_PER_BLOCK) s_cnt[tid] = counts[c0 + tid];
    if (tid == 0) {
        int end = offsets[c0 + CELLS_PER_BLOCK - 1];
        int bs  = offsets[c0] - counts[c0];        // start of first cell
        s_meta[0] = bs;
        s_meta[1] = end - bs;
    }
    __syncthreads();
    const int bs   = s_meta[0];
    const int span = s_meta[1];
    const bool staged = (span <= MAXSPAN);
    if (staged) {
        for (int i = tid; i < span; i += 256) {
            s_order[i] = order[bs + i];
            s_ocell[i] = ordcell[bs + i] - c0;     // cell-local index
        }
    }
    __syncthreads();

    // 16 groups of 16 lanes; group g handles slots g, g+16, g+32, ...
    const int grp = tid >> 4;
    const int ch4 = tid & 15;
    for (int i = grp; i < span; i += 16) {
        int p, cl;
        if (staged) { p = s_order[i];  cl = s_ocell[i]; }
        else        { p = order[bs+i]; cl = ordcell[bs+i] - c0; }
        float4 f = feat4[(size_t)p * (NCH / 4) + ch4];
        float* a = &acc[cl * NCH + ch4 * 4];
        atomicAdd(a + 0, f.x);   // ds_add_f32 — LDS atomics, 2-way bank alias
        atomicAdd(a + 1, f.y);
        atomicAdd(a + 2, f.z);
        atomicAdd(a + 3, f.w);
    }
    __syncthreads();

    // Epilogue: thread t -> cell cl=t>>2, quarter q=t&3 (4 float4 each).
    const int cl = tid >> 2;
    const int q  = tid & 3;
    const int cnt = s_cnt[cl];
    const float inv = (cnt > 0) ? (1.0f / (float)cnt) : 0.0f;
    const float4* src = (const float4*)&acc[cl * NCH + q * 16];
    float4* dst = &out4[(size_t)(c0 + cl) * (NCH / 4) + q * 4];
    #pragma unroll
    for (int j = 0; j < 4; ++j) {
        float4 v = src[j];
        v.x *= inv; v.y *= inv; v.z *= inv; v.w *= inv;
        dst[j] = v;
    }
}

extern "C" void kernel_launch(void* const* d_in, const int* in_sizes, int n_in,
                              void* d_out, int out_size, void* d_ws, size_t ws_size,
                              hipStream_t stream)
{
    const float* feat = (const float*)d_in[0];   // (N, 64) fp32
    const float* pts  = (const float*)d_in[1];   // (N, 3)  fp32
    float* out = (float*)d_out;                  // (64,64,64,64) fp32

    const int n = in_sizes[0] / NCH;

    // Workspace (ints): counts | offsets | cellid | order | ordcell | blocksums | blockbase
    int* counts    = (int*)d_ws;                 // NCELLS
    int* offsets   = counts + NCELLS;            // NCELLS
    int* cellid    = offsets + NCELLS;           // n
    int* order     = cellid + n;                 // n
    int* ordcell   = order + n;                  // n
    int* blocksums = ordcell + n;                // SCAN_BLOCKS
    int* blockbase = blocksums + SCAN_BLOCKS;    // SCAN_BLOCKS

    hipMemsetAsync(counts, 0, (size_t)NCELLS * sizeof(int), stream);

    int t4 = (n + 3) / 4;
    int pblocks4 = (t4 + 255) / 256;
    compute_cells<<<pblocks4, 256, 0, stream>>>(pts, cellid, counts, n);

    scan_reduce   <<<SCAN_BLOCKS, 256, 0, stream>>>(counts, blocksums);
    scan_blocksums<<<1,           256, 0, stream>>>(blocksums, blockbase);
    scan_write    <<<SCAN_BLOCKS, 256, 0, stream>>>(counts, blockbase, offsets);

    build_order<<<pblocks4, 256, 0, stream>>>(cellid, offsets, order, ordcell, n);

    reduce_cells<<<NCELLS / CELLS_PER_BLOCK, 256, 0, stream>>>(
        (const float4*)feat, order, ordcell, offsets, counts, (float4*)out);
}